// Round 6
// baseline (503.506 us; speedup 1.0000x reference)
//
#include <hip/hip_runtime.h>
#include <math.h>

#define IMG_W 2048
#define IMG_H 2048
#define BATCH 8
#define MAX_PEAKS ((BATCH * IMG_H * IMG_W) / 8)   // 4194304
#define NWORDS (BATCH * IMG_H * IMG_W / 32)       // 1048576
#define NFILL 2048                                // tail-fill blocks

// ---------------------------------------------------------------------------
// K1: register-ring NMS mask, 16 rows/wave, ring depth 8, high occupancy.
// 2048 blocks; block = 4 waves; wave owns 256 cols x 16 rows; lane = 4 cols.
// Ring: slot s holds row r0-2+s (mod 8); iter i loads row r0+5+i (distance-3
// consumption), computes output row r0+i. Edge halo via per-lane pre-offset
// float2 load. Block 0 also zero-inits the ctrl words for K2's election.
// mask bit = (s > 0) && (s >= 5x5 window max)
// ---------------------------------------------------------------------------
__global__ __launch_bounds__(256, 5) void nms_mask(const float* __restrict__ scores,
                                                   unsigned* __restrict__ words,
                                                   unsigned* __restrict__ bsum2,
                                                   unsigned* __restrict__ ctrl) {
    if (blockIdx.x == 0 && threadIdx.x == 0) { ctrl[0] = 0u; ctrl[1] = 0u; }
    const int t = threadIdx.x;
    const int lane = t & 63;
    const int wv = t >> 6;            // wave in block: 0..3
    const int b = blockIdx.x;         // 0..2047
    const int img = b >> 8;           // 8 images x 256 blocks
    const int rem = b & 255;
    const int strip = rem >> 5;       // 8 column strips of 256
    const int chunk = rem & 31;       // 32 row chunks of 64
    const int r0 = chunk * 64 + wv * 16;
    const int c0 = strip * 256;
    const int cl = c0 + lane * 4;
    const size_t imgBase = (size_t)img * (IMG_H * IMG_W);

    const float* colp = scores + imgBase + cl;
    const bool leftHalf = (lane < 32);
    const bool isL = (lane == 0), isR = (lane == 63);
    const int ecol = leftHalf ? (c0 - 4) : (c0 + 256);
    const bool evalid = ((unsigned)ecol < IMG_W);
    const int ecolC = evalid ? ecol : c0;
    // left lanes need (ecol+2, ecol+3); right lanes (ecol, ecol+1)
    const float* ecolp2 = scores + imgBase + ecolC + (leftHalf ? 2 : 0);

    const float NEG = -INFINITY;
    float4 R[8];
    float2 E[8];

    // prologue: rows r0-2 .. r0+4 -> slots 0..6 (low-clamped addresses)
#pragma unroll
    for (int m = 0; m < 7; ++m) {
        int gr = r0 - 2 + m;
        int rc = gr < 0 ? 0 : gr;               // r0+4 <= 2036, always valid
        size_t off = (size_t)rc * IMG_W;
        R[m] = *(const float4*)(colp + off);
        E[m] = *(const float2*)(ecolp2 + off);
    }
    if (r0 == 0) {                              // wave-uniform fixup
        R[0] = R[1] = make_float4(NEG, NEG, NEG, NEG);
        E[0] = E[1] = make_float2(NEG, NEG);
    }
    const bool bot = (r0 + 16) >= IMG_H;        // rows r0+16/17 OOB

    unsigned cnt = 0;
    const int shamt = (lane & 7) * 4;
    size_t wIdx = (size_t)(img * IMG_H + r0) * (IMG_W / 32) + strip * 8 + (lane >> 3);
    const int cb = (img * IMG_H + r0) >> 4;     // 16-row compact-block index
    const bool writer = ((lane & 7) == 0);

#pragma unroll
    for (int i = 0; i < 16; ++i) {
        // load row r0+5+i -> slot (7+i)&7 (consumed at iter i+3)
        if (i < 13) {
            int gr = r0 + 5 + i;
            int rc = gr > IMG_H - 1 ? IMG_H - 1 : gr;
            size_t off = (size_t)rc * IMG_W;
            float4 v = *(const float4*)(colp + off);
            float2 e = *(const float2*)(ecolp2 + off);
            if (i >= 11 && bot) {               // rows r0+16, r0+17
                v = make_float4(NEG, NEG, NEG, NEG);
                e = make_float2(NEG, NEG);
            }
            R[(7 + i) & 7] = v;
            E[(7 + i) & 7] = e;
        }

        // compute output row r0+i from slots i..i+4 (mod 8)
        const float4 w0 = R[(i) & 7];
        const float4 w1 = R[(i + 1) & 7];
        const float4 mid = R[(i + 2) & 7];
        const float4 w3 = R[(i + 3) & 7];
        const float4 w4 = R[(i + 4) & 7];
        float vmx = fmaxf(fmaxf(fmaxf(w0.x, w1.x), fmaxf(mid.x, w3.x)), w4.x);
        float vmy = fmaxf(fmaxf(fmaxf(w0.y, w1.y), fmaxf(mid.y, w3.y)), w4.y);
        float vmz = fmaxf(fmaxf(fmaxf(w0.z, w1.z), fmaxf(mid.z, w3.z)), w4.z);
        float vmw = fmaxf(fmaxf(fmaxf(w0.w, w1.w), fmaxf(mid.w, w3.w)), w4.w);
        const float2 e0 = E[(i) & 7];
        const float2 e1 = E[(i + 1) & 7];
        const float2 e2 = E[(i + 2) & 7];
        const float2 e3 = E[(i + 3) & 7];
        const float2 e4 = E[(i + 4) & 7];
        float vex = fmaxf(fmaxf(fmaxf(e0.x, e1.x), fmaxf(e2.x, e3.x)), e4.x);
        float vey = fmaxf(fmaxf(fmaxf(e0.y, e1.y), fmaxf(e2.y, e3.y)), e4.y);
        float eX = evalid ? vex : NEG;
        float eY = evalid ? vey : NEG;

        float A = __shfl_up(vmz, 1);
        float B = __shfl_up(vmw, 1);
        float C = __shfl_down(vmx, 1);
        float D = __shfl_down(vmy, 1);
        if (isL) { A = eX; B = eY; }
        if (isR) { C = eX; D = eY; }

        float t12 = fmaxf(vmy, vmz);
        float m02 = fmaxf(vmx, t12);
        float m03 = fmaxf(m02, vmw);
        float m13 = fmaxf(t12, vmw);
        float h0 = fmaxf(fmaxf(A, B), m02);
        float h1 = fmaxf(B, m03);
        float h2 = fmaxf(m03, C);
        float h3 = fmaxf(m13, fmaxf(C, D));

        unsigned nib = 0;
        nib |= (mid.x > 0.0f && mid.x >= h0) ? 1u : 0u;
        nib |= (mid.y > 0.0f && mid.y >= h1) ? 2u : 0u;
        nib |= (mid.z > 0.0f && mid.z >= h2) ? 4u : 0u;
        nib |= (mid.w > 0.0f && mid.w >= h3) ? 8u : 0u;

        unsigned wd = nib << shamt;
        wd |= __shfl_xor(wd, 1);
        wd |= __shfl_xor(wd, 2);
        wd |= __shfl_xor(wd, 4);
        if (writer) {
            words[wIdx] = wd;
            cnt += __popc(wd);
        }
        wIdx += IMG_W / 32;
    }

    // single flush: wave covers exactly one 16-row compact block
    unsigned s = cnt;
    s += __shfl_xor(s, 1);
    s += __shfl_xor(s, 2);
    s += __shfl_xor(s, 4);
    s += __shfl_xor(s, 8);
    s += __shfl_xor(s, 16);
    s += __shfl_xor(s, 32);
    if (lane == 0) bsum2[cb * 8 + strip] = s;
}

// ---------------------------------------------------------------------------
// K2: fused scan + ordered compaction + tail fill. Grid = 1024 + NFILL.
// First-arriving block (atomicCAS election on ctrl[0]) performs the
// exclusive scan of the 8192 strip-sums into base[0..1023] + base[1024]=
// total, then release-stores ctrl[1]=1. All blocks prefetch their words
// BEFORE spinning (overlaps loads with the scan), then acquire-spin.
// ---------------------------------------------------------------------------
__global__ __launch_bounds__(256) void nms_finish(const unsigned* __restrict__ words,
                                                  const unsigned* __restrict__ bsum2,
                                                  unsigned* __restrict__ base,
                                                  unsigned* __restrict__ ctrl,
                                                  int* __restrict__ out) {
    const int t = threadIdx.x;
    const int b = blockIdx.x;
    const int lane = t & 63, wid = t >> 6;

    // prefetch compact payload before any waiting
    uint4 q = make_uint4(0u, 0u, 0u, 0u);
    if (b < 1024) q = ((const uint4*)(words + b * 1024))[t];

    __shared__ unsigned sWin;
    if (t == 0) {
        unsigned old = atomicCAS(&ctrl[0], 0u, (unsigned)b + 1u);
        sWin = (old == 0u) ? 1u : 0u;
    }
    __syncthreads();

    if (sWin) {
        // ---- scan: 8 strip-sums per cb -> 1024 cbs, exclusive scan ----
        __shared__ unsigned wtot[4];
        const uint4* p = (const uint4*)(bsum2 + t * 32);
        unsigned c[4];
#pragma unroll
        for (int i = 0; i < 4; ++i) {
            uint4 a = p[2 * i], bq = p[2 * i + 1];
            c[i] = a.x + a.y + a.z + a.w + bq.x + bq.y + bq.z + bq.w;
        }
        unsigned s0 = c[0], s1 = s0 + c[1], s2 = s1 + c[2], ts = s2 + c[3];
        unsigned sc = ts;
#pragma unroll
        for (int d = 1; d < 64; d <<= 1) {
            unsigned o = __shfl_up(sc, d);
            if (lane >= d) sc += o;
        }
        if (lane == 63) wtot[wid] = sc;
        __syncthreads();
        unsigned wpre = 0;
#pragma unroll
        for (int k = 0; k < 4; ++k) wpre += (k < wid) ? wtot[k] : 0u;
        unsigned excl = wpre + sc - ts;
        ((uint4*)base)[t] = make_uint4(excl, excl + s0, excl + s1, excl + s2);
        if (t == 255) base[1024] = wpre + sc;
        __threadfence();          // device-scope: flush scan results
        __syncthreads();
        if (t == 0)
            __hip_atomic_store(&ctrl[1], 1u, __ATOMIC_RELEASE,
                               __HIP_MEMORY_SCOPE_AGENT);
    }

    // acquire-spin until scan published (winner falls through immediately)
    while (__hip_atomic_load(&ctrl[1], __ATOMIC_ACQUIRE,
                             __HIP_MEMORY_SCOPE_AGENT) != 1u)
        __builtin_amdgcn_s_sleep(32);

    if (b < 1024) {
        // ---- ordered compaction ----
        __shared__ unsigned wq[4];
        unsigned wv[4] = {q.x, q.y, q.z, q.w};
        unsigned tsum = __popc(wv[0]) + __popc(wv[1]) + __popc(wv[2]) + __popc(wv[3]);
        unsigned sc = tsum;
#pragma unroll
        for (int d = 1; d < 64; d <<= 1) {
            unsigned o = __shfl_up(sc, d);
            if (lane >= d) sc += o;
        }
        if (lane == 63) wq[wid] = sc;
        __syncthreads();
        unsigned wpre = 0;
#pragma unroll
        for (int k = 0; k < 4; ++k) wpre += (k < wid) ? wq[k] : 0u;
        unsigned off = base[b] + wpre + sc - tsum;

        const unsigned gword0 = (unsigned)b * 1024u + (unsigned)t * 4u;
#pragma unroll
        for (int wi = 0; wi < 4; ++wi) {
            unsigned m = wv[wi];
            unsigned pbase = (gword0 + wi) << 5;
            while (m) {
                int bit = __builtin_ctz(m);
                m &= m - 1;
                unsigned ppix = pbase + (unsigned)bit;
                int hh = (int)((ppix >> 11) & 2047u);
                int ww = (int)(ppix & 2047u);
                if (off < (unsigned)MAX_PEAKS) {
                    out[off] = hh;
                    out[MAX_PEAKS + off] = ww;
                }
                ++off;
            }
        }
    } else {
        // ---- -1 tail fill ----
        unsigned total = base[1024];
        if (total > (unsigned)MAX_PEAKS) total = MAX_PEAKS;
        unsigned tail = (unsigned)MAX_PEAKS - total;
        unsigned fb = (unsigned)(b - 1024);
        unsigned per = (tail + NFILL - 1) / NFILL;
        unsigned s = total + fb * per;
        unsigned e = s + per;
        if (e > (unsigned)MAX_PEAKS) e = MAX_PEAKS;
        for (unsigned k = s + t; k < e; k += 256) {
            out[k] = -1;
            out[MAX_PEAKS + k] = -1;
        }
    }
}

extern "C" void kernel_launch(void* const* d_in, const int* in_sizes, int n_in,
                              void* d_out, int out_size, void* d_ws, size_t ws_size,
                              hipStream_t stream) {
    const float* scores = (const float*)d_in[0];
    int* out = (int*)d_out;
    unsigned* words = (unsigned*)d_ws;            // 1,048,576 words (4 MB)
    unsigned* bsum2 = words + NWORDS;             // 8192 per-(cb,strip) sums
    unsigned* base = bsum2 + 8192;                // 1025 (incl. total)
    unsigned* ctrl = base + 1028;                 // 2 control words (aligned)

    nms_mask<<<2048, 256, 0, stream>>>(scores, words, bsum2, ctrl);
    nms_finish<<<1024 + NFILL, 256, 0, stream>>>(words, bsum2, base, ctrl, out);
}

// Round 7
// 213.867 us; speedup vs baseline: 2.3543x; 2.3543x over previous
//
#include <hip/hip_runtime.h>
#include <math.h>

#define IMG_W 2048
#define IMG_H 2048
#define BATCH 8
#define MAX_PEAKS ((BATCH * IMG_H * IMG_W) / 8)   // 4194304
#define NWORDS (BATCH * IMG_H * IMG_W / 32)       // 1048576
#define NFILL 2048                                // tail-fill blocks

// ---------------------------------------------------------------------------
// K1: shuffle-free register-ring NMS mask.
// Wave owns 256 cols x 32 rows; lane owns 4 output cols and loads TWO
// overlapping float4s per row: L=[cl-2..cl+1], R=[cl+2..cl+5] -> all 8
// columns needed for its 4 outputs live in-lane; NO cross-lane shuffles on
// the compute path (L1 absorbs the 2x load overlap; HBM fetch unchanged).
// Image borders: per-lane clamped pointers + loop-invariant remap selects.
// Ring depth 8 (rows), distance-3 prefetch, full unroll.
// Pack: 3 shfl_xor OR-reduce (off critical path); count: per-lane popc.
// mask bit = (s > 0) && (s >= 5x5 window max)
// ---------------------------------------------------------------------------
__global__ __launch_bounds__(256, 4) void nms_mask(const float* __restrict__ scores,
                                                   unsigned* __restrict__ words,
                                                   unsigned* __restrict__ bsum2) {
    const int t = threadIdx.x;
    const int lane = t & 63;
    const int wv = t >> 6;            // wave in block: 0..3
    const int b = blockIdx.x;         // 0..1023
    const int img = b >> 7;           // 8 images x 128 blocks
    const int rem = b & 127;
    const int strip = rem >> 4;       // 8 column strips of 256
    const int chunk = rem & 15;       // 16 row chunks of 128
    const int r0 = chunk * 128 + wv * 32;
    const int c0 = strip * 256;
    const int cl = c0 + lane * 4;
    const size_t imgBase = (size_t)img * (IMG_H * IMG_W);

    const bool lclamp = (cl == 0);             // left image edge lane
    const bool rclamp = (cl == IMG_W - 4);     // right image edge lane
    const float* Lp = scores + imgBase + (lclamp ? 0 : cl - 2);
    const float* Rp = scores + imgBase + (rclamp ? (IMG_W - 4) : cl + 2);

    const float NEG = -INFINITY;
    float4 RL[8], RR[8];

    // prologue: rows r0-2 .. r0+4 -> slots 0..6 (low-clamped addresses)
#pragma unroll
    for (int m = 0; m < 7; ++m) {
        int gr = r0 - 2 + m;
        int rc = gr < 0 ? 0 : gr;
        size_t off = (size_t)rc * IMG_W;
        RL[m] = *(const float4*)(Lp + off);
        RR[m] = *(const float4*)(Rp + off);
    }
    if (r0 == 0) {                             // wave-uniform fixup (rows -2,-1)
        RL[0] = RL[1] = make_float4(NEG, NEG, NEG, NEG);
        RR[0] = RR[1] = make_float4(NEG, NEG, NEG, NEG);
    }
    const bool bot = (r0 + 32) >= IMG_H;       // rows r0+32/33 OOB

    unsigned cnt = 0;
    const int shamt = (lane & 7) * 4;
    size_t wIdx = (size_t)(img * IMG_H + r0) * (IMG_W / 32) + strip * 8 + (lane >> 3);
    const int cb0 = (img * IMG_H + r0) >> 4;   // 16-row compact-block index
    const bool writer = ((lane & 7) == 0);

#pragma unroll
    for (int i = 0; i < 32; ++i) {
        // ---- load row r0+5+i -> slot (7+i)&7 (consumed at iter i+3) ----
        if (i < 29) {
            int gr = r0 + 5 + i;
            int rc = gr > IMG_H - 1 ? IMG_H - 1 : gr;
            size_t off = (size_t)rc * IMG_W;
            float4 lv = *(const float4*)(Lp + off);
            float4 rv = *(const float4*)(Rp + off);
            if (i >= 27 && bot) {              // rows r0+32, r0+33
                lv = make_float4(NEG, NEG, NEG, NEG);
                rv = make_float4(NEG, NEG, NEG, NEG);
            }
            RL[(7 + i) & 7] = lv;
            RR[(7 + i) & 7] = rv;
        }

        // ---- vertical 5-max over slots i..i+4 (rows r0+i-2..r0+i+2) ----
        const float4 a0 = RL[(i) & 7],     b0 = RR[(i) & 7];
        const float4 a1 = RL[(i + 1) & 7], b1 = RR[(i + 1) & 7];
        const float4 a2 = RL[(i + 2) & 7], b2 = RR[(i + 2) & 7];
        const float4 a3 = RL[(i + 3) & 7], b3 = RR[(i + 3) & 7];
        const float4 a4 = RL[(i + 4) & 7], b4 = RR[(i + 4) & 7];
        float Lvx = fmaxf(fmaxf(fmaxf(a0.x, a1.x), fmaxf(a2.x, a3.x)), a4.x);
        float Lvy = fmaxf(fmaxf(fmaxf(a0.y, a1.y), fmaxf(a2.y, a3.y)), a4.y);
        float Lvz = fmaxf(fmaxf(fmaxf(a0.z, a1.z), fmaxf(a2.z, a3.z)), a4.z);
        float Lvw = fmaxf(fmaxf(fmaxf(a0.w, a1.w), fmaxf(a2.w, a3.w)), a4.w);
        float Rvx = fmaxf(fmaxf(fmaxf(b0.x, b1.x), fmaxf(b2.x, b3.x)), b4.x);
        float Rvy = fmaxf(fmaxf(fmaxf(b0.y, b1.y), fmaxf(b2.y, b3.y)), b4.y);
        float Rvz = fmaxf(fmaxf(fmaxf(b0.z, b1.z), fmaxf(b2.z, b3.z)), b4.z);
        float Rvw = fmaxf(fmaxf(fmaxf(b0.w, b1.w), fmaxf(b2.w, b3.w)), b4.w);

        // ---- border remap (loop-invariant predicates) ----
        float v0 = lclamp ? NEG : Lvx;
        float v1 = lclamp ? NEG : Lvy;
        float v2 = lclamp ? Lvx : Lvz;
        float v3 = lclamp ? Lvy : Lvw;
        float v4 = rclamp ? Rvz : Rvx;
        float v5 = rclamp ? Rvw : Rvy;
        float v6 = rclamp ? NEG : Rvz;
        float v7 = rclamp ? NEG : Rvw;

        // ---- horizontal 5-max: out col j = max(v[j..j+4]) ----
        float m12 = fmaxf(v1, v2);
        float m34 = fmaxf(v3, v4);
        float m56 = fmaxf(v5, v6);
        float h0 = fmaxf(fmaxf(v0, m12), m34);
        float h1 = fmaxf(fmaxf(m12, m34), v5);
        float h2 = fmaxf(fmaxf(v2, m34), m56);
        float h3 = fmaxf(fmaxf(m34, m56), v7);

        // ---- center values (mid row = slot i+2) ----
        const float4 Lm = a2, Rm = b2;
        float s0 = lclamp ? Lm.x : Lm.z;
        float s1 = lclamp ? Lm.y : Lm.w;
        float s2 = rclamp ? Rm.z : Rm.x;
        float s3 = rclamp ? Rm.w : Rm.y;

        unsigned nib = 0;
        nib |= (s0 > 0.0f && s0 >= h0) ? 1u : 0u;
        nib |= (s1 > 0.0f && s1 >= h1) ? 2u : 0u;
        nib |= (s2 > 0.0f && s2 >= h2) ? 4u : 0u;
        nib |= (s3 > 0.0f && s3 >= h3) ? 8u : 0u;
        cnt += __popc(nib);

        unsigned wd = nib << shamt;
        wd |= __shfl_xor(wd, 1);
        wd |= __shfl_xor(wd, 2);
        wd |= __shfl_xor(wd, 4);
        if (writer) words[wIdx] = wd;
        wIdx += IMG_W / 32;

        if (i == 15 || i == 31) {   // flush per 16 rows
            unsigned s = cnt;
            s += __shfl_xor(s, 1);
            s += __shfl_xor(s, 2);
            s += __shfl_xor(s, 4);
            s += __shfl_xor(s, 8);
            s += __shfl_xor(s, 16);
            s += __shfl_xor(s, 32);
            if (lane == 0) bsum2[(cb0 + (i >> 4)) * 8 + strip] = s;
            cnt = 0;
        }
    }
}

// ---------------------------------------------------------------------------
// K2: scan. Reduce 8 strip-sums per 16-row chunk (8192 slots -> 1024 cbs),
// exclusive scan, base[1024] = total. One 256-thread block.
// ---------------------------------------------------------------------------
__global__ __launch_bounds__(256) void nms_scan(const unsigned* __restrict__ bsum2,
                                                unsigned* __restrict__ base) {
    __shared__ unsigned wtot[4];
    const int t = threadIdx.x;
    const int lane = t & 63, wid = t >> 6;
    const uint4* p = (const uint4*)(bsum2 + t * 32);   // 4 cbs x 8 slots
    unsigned c[4];
#pragma unroll
    for (int i = 0; i < 4; ++i) {
        uint4 a = p[2 * i], bq = p[2 * i + 1];
        c[i] = a.x + a.y + a.z + a.w + bq.x + bq.y + bq.z + bq.w;
    }
    unsigned s0 = c[0], s1 = s0 + c[1], s2 = s1 + c[2], ts = s2 + c[3];
    unsigned sc = ts;
#pragma unroll
    for (int d = 1; d < 64; d <<= 1) {
        unsigned o = __shfl_up(sc, d);
        if (lane >= d) sc += o;
    }
    if (lane == 63) wtot[wid] = sc;
    __syncthreads();
    unsigned wpre = 0;
#pragma unroll
    for (int k = 0; k < 4; ++k) wpre += (k < wid) ? wtot[k] : 0u;
    unsigned excl = wpre + sc - ts;
    ((uint4*)base)[t] = make_uint4(excl, excl + s0, excl + s1, excl + s2);
    if (t == 255) base[1024] = wpre + sc;
}

// ---------------------------------------------------------------------------
// K3: ordered compaction (blocks 0..1023) + -1 tail fill (blocks 1024..)
// ---------------------------------------------------------------------------
__global__ __launch_bounds__(256) void nms_compact(const unsigned* __restrict__ words,
                                                   const unsigned* __restrict__ base,
                                                   int* __restrict__ out) {
    const int t = threadIdx.x;
    const int b = blockIdx.x;
    if (b < 1024) {
        __shared__ unsigned wq[4];
        const int lane = t & 63, wid = t >> 6;
        uint4 q = ((const uint4*)(words + b * 1024))[t];
        unsigned wv[4] = {q.x, q.y, q.z, q.w};
        unsigned tsum = __popc(wv[0]) + __popc(wv[1]) + __popc(wv[2]) + __popc(wv[3]);
        unsigned sc = tsum;
#pragma unroll
        for (int d = 1; d < 64; d <<= 1) {
            unsigned o = __shfl_up(sc, d);
            if (lane >= d) sc += o;
        }
        if (lane == 63) wq[wid] = sc;
        __syncthreads();
        unsigned wpre = 0;
#pragma unroll
        for (int k = 0; k < 4; ++k) wpre += (k < wid) ? wq[k] : 0u;
        unsigned off = base[b] + wpre + sc - tsum;

        const unsigned gword0 = (unsigned)b * 1024u + (unsigned)t * 4u;
#pragma unroll
        for (int wi = 0; wi < 4; ++wi) {
            unsigned m = wv[wi];
            unsigned pbase = (gword0 + wi) << 5;
            while (m) {
                int bit = __builtin_ctz(m);
                m &= m - 1;
                unsigned ppix = pbase + (unsigned)bit;
                int hh = (int)((ppix >> 11) & 2047u);
                int ww = (int)(ppix & 2047u);
                if (off < (unsigned)MAX_PEAKS) {
                    out[off] = hh;
                    out[MAX_PEAKS + off] = ww;
                }
                ++off;
            }
        }
    } else {
        unsigned total = base[1024];
        if (total > (unsigned)MAX_PEAKS) total = MAX_PEAKS;
        unsigned tail = (unsigned)MAX_PEAKS - total;
        unsigned fb = (unsigned)(b - 1024);
        unsigned per = (tail + NFILL - 1) / NFILL;
        unsigned s = total + fb * per;
        unsigned e = s + per;
        if (e > (unsigned)MAX_PEAKS) e = MAX_PEAKS;
        for (unsigned k = s + t; k < e; k += 256) {
            out[k] = -1;
            out[MAX_PEAKS + k] = -1;
        }
    }
}

extern "C" void kernel_launch(void* const* d_in, const int* in_sizes, int n_in,
                              void* d_out, int out_size, void* d_ws, size_t ws_size,
                              hipStream_t stream) {
    const float* scores = (const float*)d_in[0];
    int* out = (int*)d_out;
    unsigned* words = (unsigned*)d_ws;            // 1,048,576 words (4 MB)
    unsigned* bsum2 = words + NWORDS;             // 8192 per-(cb,strip) sums
    unsigned* base = bsum2 + 8192;                // 1025 (incl. total)

    nms_mask<<<1024, 256, 0, stream>>>(scores, words, bsum2);
    nms_scan<<<1, 256, 0, stream>>>(bsum2, base);
    nms_compact<<<1024 + NFILL, 256, 0, stream>>>(words, base, out);
}